// Round 4
// baseline (450.524 us; speedup 1.0000x reference)
//
#include <hip/hip_runtime.h>

typedef unsigned short u16;
typedef unsigned int   u32;

#define NB 256   // batch
#define NS 1024  // seq

// ---------------- y_trans = l2norm(prelu(y @ w_ty + b_ty)) : [256][128] fp32 ----------------
__global__ void yn_kernel(const float* __restrict__ y, const float* __restrict__ wty,
                          const float* __restrict__ bty, const float* __restrict__ aty,
                          float* __restrict__ yn)
{
    __shared__ float yl[64];
    __shared__ float sq[128];
    int b = blockIdx.x, t = threadIdx.x;
    if (t < 64) yl[t] = y[b*64 + t];
    __syncthreads();
    float acc = bty[t];
    for (int k = 0; k < 64; ++k) acc = fmaf(yl[k], wty[k*128 + t], acc);
    float a = aty[0];
    float v = (acc >= 0.f) ? acc : a * acc;
    sq[t] = v * v;
    __syncthreads();
    for (int s = 64; s >= 1; s >>= 1) { if (t < s) sq[t] += sq[t+s]; __syncthreads(); }
    float inv = 1.f / fmaxf(sqrtf(sq[0]), 1e-12f);
    yn[b*128 + t] = v * inv;
}

// ---------------- main fused kernel: one block per (chunk, b, branch) ----------------
// All-fp32 LDS, no type-punning, no input-side bf16 quantization.
__global__ __launch_bounds__(256, 2) void main_kernel(
    const float* __restrict__ xloc, const float* __restrict__ xnon,
    const float* __restrict__ uid,  const float* __restrict__ ose, const float* __restrict__ zipc,
    const float* __restrict__ wlx,  const float* __restrict__ blx, const float* __restrict__ alx,
    const float* __restrict__ wnx,  const float* __restrict__ bnx, const float* __restrict__ anx,
    const float* __restrict__ lw1,  const float* __restrict__ lb1, const float* __restrict__ la1,
    const float* __restrict__ lw2,  const float* __restrict__ lb2,
    const float* __restrict__ nw1,  const float* __restrict__ nb1, const float* __restrict__ na1,
    const float* __restrict__ nw2,  const float* __restrict__ nb2,
    const float* __restrict__ yn, float* __restrict__ pacc)
{
    __shared__ float xs[64*65];     // x tile [r][k], stride 65
    __shared__ float tn[64*129];    // normalized t [r][c], stride 129
    __shared__ float Weff[2*64*40]; // [h][d][j] fp32
    __shared__ float Cs[80];        // [h][j]
    __shared__ float red[1152];     // sumsq partials [64][17] / p partials [128][9] / final combine
    __shared__ float rninv[64];
    __shared__ float ps[128];       // p [h][r]

    const int tid   = threadIdx.x;
    const int chunk = blockIdx.x;   // 0..3  (256 rows each)
    const int b     = blockIdx.y;   // 0..255
    const int br    = blockIdx.z;   // 0 local, 1 nonlocal

    const float* xg   = br ? xnon : xloc;
    const float* W    = br ? wnx  : wlx;
    const float* bias = br ? bnx  : blx;
    const float* alp  = br ? anx  : alx;
    const float* w1   = br ? nw1  : lw1;
    const float* b1   = br ? nb1  : lb1;
    const float* a1p  = br ? na1  : la1;
    const float* w2   = br ? nw2  : lw2;
    const float* b2p  = br ? nb2  : lb2;

    // W_eff[h][d][j] = w1a[d][j] + w1c[d][j] + yh[d]*w1b[d][j]
    for (int idx = tid; idx < 5120; idx += 256) {
        int j = idx % 40; int rest = idx / 40; int d = rest & 63; int h = rest >> 6;
        float yv = yn[b*128 + h*64 + d];
        float v = w1[d*40 + j] + w1[(128+d)*40 + j] + yv * w1[(64+d)*40 + j];
        Weff[(h*64 + d)*40 + j] = v;
    }
    // C[h][j] = b1[j] + yh@(w1d - w1c) + side@w1e
    if (tid < 80) {
        int h = tid / 40, j = tid % 40;
        float acc = b1[j];
        for (int d = 0; d < 64; ++d) {
            float yv = yn[b*128 + h*64 + d];
            acc = fmaf(yv, w1[(192+d)*40 + j] - w1[(128+d)*40 + j], acc);
        }
        for (int t2 = 0; t2 < 32; ++t2) acc = fmaf(uid[b*32+t2],  w1[(256+t2)*40 + j], acc);
        for (int t2 = 0; t2 < 8;  ++t2) acc = fmaf(ose[b*8 +t2],  w1[(288+t2)*40 + j], acc);
        for (int t2 = 0; t2 < 16; ++t2) acc = fmaf(zipc[b*16+t2], w1[(296+t2)*40 + j], acc);
        Cs[h*40 + j] = acc;
    }
    const float ax  = alp[0];
    const float a1  = a1p[0];
    const float b2v = b2p[0];

    const int tr  = tid >> 4;        // row group 0..15 (rows tr*4..tr*4+3)
    const int tcg = tid & 15;        // col group (B: 8 cols; C: head*jgroup)
    const int h_c = tcg >> 3;        // phase C head
    const int j0  = (tcg & 7) * 5;   // phase C j base

    const int hD = (tid >> 6) & 1;   // phase D head
    const int dD = tid & 63;         // phase D dim
    const int rh = tid >> 7;         // phase D row half

    // per-thread constants from global (broadcast / L1)
    float bv[8];
    #pragma unroll
    for (int cc = 0; cc < 8; ++cc) bv[cc] = bias[tcg*8 + cc];
    float w2v[5];
    #pragma unroll
    for (int i = 0; i < 5; ++i) w2v[i] = w2[j0 + i];

    __syncthreads();

    float outacc = 0.f;

    for (int st = 0; st < 4; ++st) {
        const int s0 = chunk*256 + st*64;
        __syncthreads();  // protect xs/tn vs previous iteration readers

        // ---- Phase A: load x subtile fp32 -> LDS [r][k] stride 65 ----
        for (int i = tid; i < 4096; i += 256) {
            int r = i >> 6, k = i & 63;
            xs[r*65 + k] = xg[((size_t)b*NS + s0 + r)*64 + k];
        }
        __syncthreads();

        // ---- Phase B: t = prelu(x @ W + bias), 4 rows x 8 cols per thread ----
        float acc[4][8];
        #pragma unroll
        for (int rr = 0; rr < 4; ++rr)
            #pragma unroll
            for (int cc = 0; cc < 8; ++cc) acc[rr][cc] = bv[cc];

        for (int k = 0; k < 64; ++k) {
            float xv[4];
            #pragma unroll
            for (int rr = 0; rr < 4; ++rr) xv[rr] = xs[(tr*4+rr)*65 + k];
            const float* wrow = &W[k*128 + tcg*8];
            float4 wa = *(const float4*)(wrow);
            float4 wb = *(const float4*)(wrow + 4);
            float wv[8] = { wa.x, wa.y, wa.z, wa.w, wb.x, wb.y, wb.z, wb.w };
            #pragma unroll
            for (int rr = 0; rr < 4; ++rr)
                #pragma unroll
                for (int cc = 0; cc < 8; ++cc)
                    acc[rr][cc] = fmaf(xv[rr], wv[cc], acc[rr][cc]);
        }
        // prelu + row sum-of-squares partials
        #pragma unroll
        for (int rr = 0; rr < 4; ++rr) {
            float s = 0.f;
            #pragma unroll
            for (int cc = 0; cc < 8; ++cc) {
                float v = acc[rr][cc];
                v = (v >= 0.f) ? v : ax * v;
                acc[rr][cc] = v;
                s = fmaf(v, v, s);
            }
            red[(tr*4+rr)*17 + tcg] = s;
        }
        __syncthreads();
        if (tid < 64) {
            float s = 0.f;
            #pragma unroll
            for (int j = 0; j < 16; ++j) s += red[tid*17 + j];
            rninv[tid] = 1.f / fmaxf(sqrtf(s), 1e-12f);
        }
        __syncthreads();
        // normalized tn -> LDS fp32 [r][c] stride 129
        #pragma unroll
        for (int rr = 0; rr < 4; ++rr) {
            float ri = rninv[tr*4+rr];
            #pragma unroll
            for (int cc = 0; cc < 8; ++cc)
                tn[(tr*4+rr)*129 + tcg*8 + cc] = acc[rr][cc] * ri;
        }
        __syncthreads();

        // ---- Phase C: h1 = prelu(tn_head @ Weff + C); p = h1 @ w2 + b2 ----
        float h1a[4][5];
        #pragma unroll
        for (int rr = 0; rr < 4; ++rr)
            #pragma unroll
            for (int i = 0; i < 5; ++i) h1a[rr][i] = Cs[h_c*40 + j0 + i];

        for (int k = 0; k < 64; ++k) {
            float tv[4];
            #pragma unroll
            for (int rr = 0; rr < 4; ++rr) tv[rr] = tn[(tr*4+rr)*129 + h_c*64 + k];
            const float* wp = &Weff[(h_c*64+k)*40 + j0];
            float wv0 = wp[0], wv1 = wp[1], wv2 = wp[2], wv3 = wp[3], wv4 = wp[4];
            #pragma unroll
            for (int rr = 0; rr < 4; ++rr) {
                h1a[rr][0] = fmaf(tv[rr], wv0, h1a[rr][0]);
                h1a[rr][1] = fmaf(tv[rr], wv1, h1a[rr][1]);
                h1a[rr][2] = fmaf(tv[rr], wv2, h1a[rr][2]);
                h1a[rr][3] = fmaf(tv[rr], wv3, h1a[rr][3]);
                h1a[rr][4] = fmaf(tv[rr], wv4, h1a[rr][4]);
            }
        }
        #pragma unroll
        for (int rr = 0; rr < 4; ++rr) {
            float pp = 0.f;
            #pragma unroll
            for (int i = 0; i < 5; ++i) {
                float v = h1a[rr][i];
                v = (v >= 0.f) ? v : a1 * v;
                pp = fmaf(v, w2v[i], pp);
            }
            red[(h_c*64 + tr*4 + rr)*9 + (tcg & 7)] = pp;
        }
        __syncthreads();
        if (tid < 128) {
            int h = tid >> 6, row = tid & 63;
            float p = b2v;
            #pragma unroll
            for (int j = 0; j < 8; ++j) p += red[(h*64+row)*9 + j];
            ps[tid] = p;
        }
        __syncthreads();

        // ---- Phase D: out[h][d] += sum_r tn[r][h*64+d] * p[h][r] ----
        {
            const int c = hD*64 + dD;
            #pragma unroll
            for (int r = rh*32; r < rh*32 + 32; ++r)
                outacc = fmaf(tn[r*129 + c], ps[hD*64 + r], outacc);
        }
    }

    // combine the two row-halves, store fp32 partial per (branch,b,chunk)
    __syncthreads();
    if (tid >= 128) red[tid - 128] = outacc;
    __syncthreads();
    if (tid < 128) {
        float tot = outacc + red[tid];
        pacc[(((size_t)br*NB + b)*4 + chunk)*128 + tid] = tot;
    }
}

// ---------------- finalize: sum 4 chunk partials, store FP32 (output dtype = float32) ----------------
__global__ void fin_kernel(const float* __restrict__ pacc, float* __restrict__ out)
{
    int g = blockIdx.x*256 + threadIdx.x;   // < 65536
    int br = g >> 15, rem = g & 32767;
    int b = rem >> 7, hd = rem & 127;
    const float* p = pacc + (((size_t)br*NB + b)*4)*128 + hd;
    float s = p[0] + p[128] + p[256] + p[384];
    out[g] = s;
}

extern "C" void kernel_launch(void* const* d_in, const int* in_sizes, int n_in,
                              void* d_out, int out_size, void* d_ws, size_t ws_size,
                              hipStream_t stream)
{
    const float* xl  = (const float*)d_in[0];
    const float* xn  = (const float*)d_in[1];
    const float* y   = (const float*)d_in[2];
    const float* uid = (const float*)d_in[3];
    const float* ose = (const float*)d_in[4];
    const float* zp  = (const float*)d_in[5];
    const float* wty = (const float*)d_in[6];
    const float* bty = (const float*)d_in[7];
    const float* aty = (const float*)d_in[8];
    const float* wlx = (const float*)d_in[9];
    const float* blx = (const float*)d_in[10];
    const float* alx = (const float*)d_in[11];
    const float* wnx = (const float*)d_in[12];
    const float* bnx = (const float*)d_in[13];
    const float* anx = (const float*)d_in[14];
    const float* lw1 = (const float*)d_in[15];
    const float* lb1 = (const float*)d_in[16];
    const float* la1 = (const float*)d_in[17];
    const float* lw2 = (const float*)d_in[18];
    const float* lb2 = (const float*)d_in[19];
    const float* nw1 = (const float*)d_in[20];
    const float* nb1 = (const float*)d_in[21];
    const float* na1 = (const float*)d_in[22];
    const float* nw2 = (const float*)d_in[23];
    const float* nb2 = (const float*)d_in[24];

    float* yn   = (float*)d_ws;            // 256*128 fp32
    float* pacc = (float*)d_ws + 32768;    // 2*256*4*128 fp32

    yn_kernel<<<dim3(256), dim3(128), 0, stream>>>(y, wty, bty, aty, yn);
    main_kernel<<<dim3(4, 256, 2), dim3(256), 0, stream>>>(
        xl, xn, uid, ose, zp,
        wlx, blx, alx, wnx, bnx, anx,
        lw1, lb1, la1, lw2, lb2,
        nw1, nb1, na1, nw2, nb2,
        yn, pacc);
    fin_kernel<<<dim3(256), dim3(256), 0, stream>>>(pacc, (float*)d_out);
}

// Round 5
// 337.041 us; speedup vs baseline: 1.3367x; 1.3367x over previous
//
#include <hip/hip_runtime.h>

typedef unsigned short u16;
typedef unsigned int   u32;

typedef __attribute__((ext_vector_type(8))) short bf8_t;   // 8 x bf16 (4 VGPRs)
typedef __attribute__((ext_vector_type(4))) float f4_t;    // 4 x fp32 acc

#define NB 256
#define NS 1024

__device__ __forceinline__ u16 f2bf(float f){
    u32 u = __float_as_uint(f);
    u32 r = (u + 0x7fffu + ((u >> 16) & 1u)) >> 16;
    return (u16)r;
}

// ---------------- y_trans = l2norm(prelu(y @ w_ty + b_ty)) : [256][128] fp32 ----------------
__global__ void yn_kernel(const float* __restrict__ y, const float* __restrict__ wty,
                          const float* __restrict__ bty, const float* __restrict__ aty,
                          float* __restrict__ yn)
{
    __shared__ float yl[64];
    __shared__ float sq[128];
    int b = blockIdx.x, t = threadIdx.x;
    if (t < 64) yl[t] = y[b*64 + t];
    __syncthreads();
    float acc = bty[t];
    for (int k = 0; k < 64; ++k) acc = fmaf(yl[k], wty[k*128 + t], acc);
    float a = aty[0];
    float v = (acc >= 0.f) ? acc : a * acc;
    sq[t] = v * v;
    __syncthreads();
    for (int s = 64; s >= 1; s >>= 1) { if (t < s) sq[t] += sq[t+s]; __syncthreads(); }
    float inv = 1.f / fmaxf(sqrtf(sq[0]), 1e-12f);
    yn[b*128 + t] = v * inv;
}

// ---------------- main fused kernel (MFMA): one block per (chunk, b, branch) ----------------
__global__ __launch_bounds__(256, 2) void main_kernel(
    const float* __restrict__ xloc, const float* __restrict__ xnon,
    const float* __restrict__ uid,  const float* __restrict__ ose, const float* __restrict__ zipc,
    const float* __restrict__ wlx,  const float* __restrict__ blx, const float* __restrict__ alx,
    const float* __restrict__ wnx,  const float* __restrict__ bnx, const float* __restrict__ anx,
    const float* __restrict__ lw1,  const float* __restrict__ lb1, const float* __restrict__ la1,
    const float* __restrict__ lw2,  const float* __restrict__ lb2,
    const float* __restrict__ nw1,  const float* __restrict__ nb1, const float* __restrict__ na1,
    const float* __restrict__ nw2,  const float* __restrict__ nb2,
    const float* __restrict__ yn, float* __restrict__ out)
{
    __shared__ u16 xs[64*72];        // x tile bf16 [r][k], stride 72 (144B = 9*16B rows)
    __shared__ u16 tn[64*136];       // normalized t bf16 [r][c], stride 136 (17*16B)
    __shared__ u16 Wt[128*72];       // W^T bf16 [c][k], stride 72
    __shared__ u16 WeffT[96*72];     // Weff^T bf16 [(h*48+j)][k], stride 72 (j>=40 zero)
    __shared__ float Cs[96];         // [h*48+j]
    __shared__ float red[512];       // final cross-wave combine [w][c]

    const int tid   = threadIdx.x;
    const int chunk = blockIdx.x;   // 0..3  (256 rows each)
    const int b     = blockIdx.y;   // 0..255
    const int br    = blockIdx.z;   // 0 local, 1 nonlocal

    const float* xg   = br ? xnon : xloc;
    const float* W    = br ? wnx  : wlx;
    const float* bias = br ? bnx  : blx;
    const float* alp  = br ? anx  : alx;
    const float* w1   = br ? nw1  : lw1;
    const float* b1   = br ? nb1  : lb1;
    const float* a1p  = br ? na1  : la1;
    const float* w2   = br ? nw2  : lw2;
    const float* b2p  = br ? nb2  : lb2;

    // ---- stage weights (once per block) ----
    // Wt[c][k] = W[k][c]   (uncoalesced global gather, L1/L2-cached; clean LDS writes)
    for (int i = tid; i < 8192; i += 256) {
        int c = i >> 6, k = i & 63;
        Wt[c*72 + k] = f2bf(W[k*128 + c]);
    }
    // WeffT[h*48+j][k] = w1a[k][j] + w1c[k][j] + yh[k]*w1b[k][j]  (j<40; else 0)
    for (int i = tid; i < 6144; i += 256) {
        int k = i & 63, cj = i >> 6;          // cj = h*48 + j
        int h = cj / 48, j = cj % 48;
        float v = 0.f;
        if (j < 40)
            v = w1[k*40 + j] + w1[(128+k)*40 + j] + yn[b*128 + h*64 + k] * w1[(64+k)*40 + j];
        WeffT[cj*72 + k] = f2bf(v);
    }
    // Cs[h*48+j] = b1[j] + yh@(w1d - w1c) + side@w1e   (j<40; else 0)
    if (tid < 96) {
        int h = tid / 48, j = tid % 48;
        float acc = 0.f;
        if (j < 40) {
            acc = b1[j];
            for (int d = 0; d < 64; ++d) {
                float yv = yn[b*128 + h*64 + d];
                acc = fmaf(yv, w1[(192+d)*40 + j] - w1[(128+d)*40 + j], acc);
            }
            for (int t2 = 0; t2 < 32; ++t2) acc = fmaf(uid[b*32+t2],  w1[(256+t2)*40 + j], acc);
            for (int t2 = 0; t2 < 8;  ++t2) acc = fmaf(ose[b*8 +t2],  w1[(288+t2)*40 + j], acc);
            for (int t2 = 0; t2 < 16; ++t2) acc = fmaf(zipc[b*16+t2], w1[(296+t2)*40 + j], acc);
        }
        Cs[tid] = acc;
    }
    const float ax  = alp[0];
    const float a1  = a1p[0];
    const float b2v = b2p[0];

    __syncthreads();

    const int w    = tid >> 6;      // wave 0..3 -> rows w*16 .. w*16+15 of each 64-row subtile
    const int lane = tid & 63;
    const int q    = lane >> 4;     // quad 0..3
    const int lm   = lane & 15;

    // ---- preload weight fragments to VGPRs (block-constant) ----
    bf8_t Bfrag[8][2];              // phase B: B[k][n], n-tile 0..7, kstep 0..1
    #pragma unroll
    for (int n = 0; n < 8; ++n)
        #pragma unroll
        for (int ks = 0; ks < 2; ++ks)
            Bfrag[n][ks] = *(const bf8_t*)&Wt[(n*16 + lm)*72 + ks*32 + q*8];

    bf8_t Cfrag[2][3][2];           // phase C: Weff^T per head, n-tile 0..2, kstep 0..1
    #pragma unroll
    for (int h = 0; h < 2; ++h)
        #pragma unroll
        for (int nj = 0; nj < 3; ++nj)
            #pragma unroll
            for (int ks = 0; ks < 2; ++ks)
                Cfrag[h][nj][ks] = *(const bf8_t*)&WeffT[(h*48 + nj*16 + lm)*72 + ks*32 + q*8];

    float bv[8];                    // bias for col n*16+lm
    #pragma unroll
    for (int n = 0; n < 8; ++n) bv[n] = bias[n*16 + lm];
    float w2v[3];
    #pragma unroll
    for (int nj = 0; nj < 3; ++nj) w2v[nj] = (nj*16 + lm < 40) ? w2[nj*16 + lm] : 0.f;
    float Cv[2][3];
    #pragma unroll
    for (int h = 0; h < 2; ++h)
        #pragma unroll
        for (int nj = 0; nj < 3; ++nj) Cv[h][nj] = Cs[h*48 + nj*16 + lm];

    float outp[8];
    #pragma unroll
    for (int n = 0; n < 8; ++n) outp[n] = 0.f;

    const f4_t zero4 = {0.f, 0.f, 0.f, 0.f};

    for (int st = 0; st < 4; ++st) {
        const int s0 = chunk*256 + st*64;
        __syncthreads();   // xs consumers of previous subtile done

        // ---- Phase A: x rows s0..s0+63 (fp32) -> xs bf16 [r][72] ----
        for (int i = tid; i < 1024; i += 256) {
            int r = i >> 4, k4 = i & 15;
            float4 v = *(const float4*)&xg[((size_t)b*NS + s0 + r)*64 + k4*4];
            u32 p0 = (u32)f2bf(v.x) | ((u32)f2bf(v.y) << 16);
            u32 p1 = (u32)f2bf(v.z) | ((u32)f2bf(v.w) << 16);
            *(uint2*)&xs[r*72 + k4*4] = make_uint2(p0, p1);
        }
        __syncthreads();

        // ---- Phase B: t = prelu(x @ W + bias) via MFMA; wave w -> rows w*16.. ----
        bf8_t a0 = *(const bf8_t*)&xs[(w*16 + lm)*72 + 0  + q*8];
        bf8_t a1f= *(const bf8_t*)&xs[(w*16 + lm)*72 + 32 + q*8];
        f4_t accB[8];
        #pragma unroll
        for (int n = 0; n < 8; ++n) {
            f4_t acc = zero4;
            acc = __builtin_amdgcn_mfma_f32_16x16x32_bf16(a0,  Bfrag[n][0], acc, 0, 0, 0);
            acc = __builtin_amdgcn_mfma_f32_16x16x32_bf16(a1f, Bfrag[n][1], acc, 0, 0, 0);
            accB[n] = acc;
        }
        // epilogue: bias + prelu + row l2norm (rows are q*4+r, cols n*16+lm)
        float tv[8][4];
        float ssq[4] = {0.f, 0.f, 0.f, 0.f};
        #pragma unroll
        for (int n = 0; n < 8; ++n)
            #pragma unroll
            for (int r = 0; r < 4; ++r) {
                float v = accB[n][r] + bv[n];
                v = (v >= 0.f) ? v : ax * v;
                tv[n][r] = v;
                ssq[r] = fmaf(v, v, ssq[r]);
            }
        #pragma unroll
        for (int r = 0; r < 4; ++r) {
            float s = ssq[r];
            s += __shfl_xor(s, 1);
            s += __shfl_xor(s, 2);
            s += __shfl_xor(s, 4);
            s += __shfl_xor(s, 8);
            float rinv = 1.f / fmaxf(sqrtf(s), 1e-12f);
            #pragma unroll
            for (int n = 0; n < 8; ++n) tv[n][r] *= rinv;
        }
        // tn -> LDS (bf16) for the C/D->A layout transform (intra-wave rows)
        #pragma unroll
        for (int n = 0; n < 8; ++n)
            #pragma unroll
            for (int r = 0; r < 4; ++r)
                tn[(w*16 + q*4 + r)*136 + n*16 + lm] = f2bf(tv[n][r]);
        // no barrier needed: wave w reads back only rows w*16..w*16+15 (program order)

        // ---- Phase C: h1 = prelu(tn_h @ Weff + C); p = h1 @ w2 + b2 ----
        f4_t accC[2][3];
        #pragma unroll
        for (int h = 0; h < 2; ++h) {
            bf8_t ac0 = *(const bf8_t*)&tn[(w*16 + lm)*136 + h*64 + 0  + q*8];
            bf8_t ac1 = *(const bf8_t*)&tn[(w*16 + lm)*136 + h*64 + 32 + q*8];
            #pragma unroll
            for (int nj = 0; nj < 3; ++nj) {
                f4_t acc = zero4;
                acc = __builtin_amdgcn_mfma_f32_16x16x32_bf16(ac0, Cfrag[h][nj][0], acc, 0, 0, 0);
                acc = __builtin_amdgcn_mfma_f32_16x16x32_bf16(ac1, Cfrag[h][nj][1], acc, 0, 0, 0);
                accC[h][nj] = acc;
            }
        }
        float pv[2][4];
        #pragma unroll
        for (int h = 0; h < 2; ++h) {
            float pp[4] = {0.f, 0.f, 0.f, 0.f};
            #pragma unroll
            for (int nj = 0; nj < 3; ++nj)
                #pragma unroll
                for (int r = 0; r < 4; ++r) {
                    float v = accC[h][nj][r] + Cv[h][nj];
                    v = (v >= 0.f) ? v : a1 * v;
                    pp[r] = fmaf(v, w2v[nj], pp[r]);
                }
            #pragma unroll
            for (int r = 0; r < 4; ++r) {
                float s = pp[r];
                s += __shfl_xor(s, 1);
                s += __shfl_xor(s, 2);
                s += __shfl_xor(s, 4);
                s += __shfl_xor(s, 8);
                pv[h][r] = s + b2v;
            }
        }

        // ---- Phase D (in registers): out[col] += tn[row][col] * p[head(col)][row] ----
        #pragma unroll
        for (int n = 0; n < 8; ++n)
            #pragma unroll
            for (int r = 0; r < 4; ++r)
                outp[n] = fmaf(tv[n][r], pv[n >> 2][r], outp[n]);
    }

    // reduce over quads (rows within wave), then across waves via LDS, then atomic
    #pragma unroll
    for (int n = 0; n < 8; ++n) {
        float v = outp[n];
        v += __shfl_xor(v, 16);
        v += __shfl_xor(v, 32);
        outp[n] = v;
    }
    if (lane < 16) {
        #pragma unroll
        for (int n = 0; n < 8; ++n) red[w*128 + n*16 + lane] = outp[n];
    }
    __syncthreads();
    if (tid < 128) {
        float s = red[tid] + red[128 + tid] + red[256 + tid] + red[384 + tid];
        atomicAdd(&out[((size_t)br*NB + b)*128 + tid], s);
    }
}

extern "C" void kernel_launch(void* const* d_in, const int* in_sizes, int n_in,
                              void* d_out, int out_size, void* d_ws, size_t ws_size,
                              hipStream_t stream)
{
    const float* xl  = (const float*)d_in[0];
    const float* xn  = (const float*)d_in[1];
    const float* y   = (const float*)d_in[2];
    const float* uid = (const float*)d_in[3];
    const float* ose = (const float*)d_in[4];
    const float* zp  = (const float*)d_in[5];
    const float* wty = (const float*)d_in[6];
    const float* bty = (const float*)d_in[7];
    const float* aty = (const float*)d_in[8];
    const float* wlx = (const float*)d_in[9];
    const float* blx = (const float*)d_in[10];
    const float* alx = (const float*)d_in[11];
    const float* wnx = (const float*)d_in[12];
    const float* bnx = (const float*)d_in[13];
    const float* anx = (const float*)d_in[14];
    const float* lw1 = (const float*)d_in[15];
    const float* lb1 = (const float*)d_in[16];
    const float* la1 = (const float*)d_in[17];
    const float* lw2 = (const float*)d_in[18];
    const float* lb2 = (const float*)d_in[19];
    const float* nw1 = (const float*)d_in[20];
    const float* nb1 = (const float*)d_in[21];
    const float* na1 = (const float*)d_in[22];
    const float* nw2 = (const float*)d_in[23];
    const float* nb2 = (const float*)d_in[24];

    float* yn = (float*)d_ws;   // 256*128 fp32

    hipMemsetAsync(d_out, 0, (size_t)out_size * sizeof(float), stream);
    yn_kernel<<<dim3(256), dim3(128), 0, stream>>>(y, wty, bty, aty, yn);
    main_kernel<<<dim3(4, 256, 2), dim3(256), 0, stream>>>(
        xl, xn, uid, ose, zp,
        wlx, blx, alx, wnx, bnx, anx,
        lw1, lb1, la1, lw2, lb2,
        nw1, nb1, na1, nw2, nb2,
        yn, (float*)d_out);
}

// Round 6
// 305.998 us; speedup vs baseline: 1.4723x; 1.1014x over previous
//
#include <hip/hip_runtime.h>

typedef unsigned short u16;
typedef unsigned int   u32;
typedef __attribute__((ext_vector_type(8))) short bf8_t;   // 8 x bf16 (4 VGPRs)
typedef __attribute__((ext_vector_type(4))) float f4_t;    // 4 x fp32 acc

#define NB 256
#define NS 1024

__device__ __forceinline__ u16 f2bf(float f){   // RNE (used in prep only)
    u32 u = __float_as_uint(f);
    return (u16)((u + 0x7fffu + ((u >> 16) & 1u)) >> 16);
}
__device__ __forceinline__ u32 pack_trunc(float lo, float hi){  // 2 x fp32 -> packed bf16 (truncate)
    return (__float_as_uint(hi) & 0xffff0000u) | (__float_as_uint(lo) >> 16);
}

// ---- prep 1: W (x-transform) weights -> MFMA B-fragment layout, bf16 ----
// wtf unit u = (br*16 + n*2 + ks)*64 + lane : 8 bf16 = W_br[k][n*16+lm], k=ks*32+q*8+j
__global__ void prep_wtf(const float* __restrict__ wlx, const float* __restrict__ wnx,
                         u32* __restrict__ wtf)
{
    int tid = threadIdx.x;
    for (int u = tid; u < 2048; u += 256) {
        int lane = u & 63, fr = u >> 6;
        int br = fr >> 4, t = fr & 15, n = t >> 1, ks = t & 1;
        int q = lane >> 4, lm = lane & 15;
        const float* W = br ? wnx : wlx;
        u32 out[4];
        #pragma unroll
        for (int p = 0; p < 4; ++p) {
            int k = ks*32 + q*8 + p*2;
            float lo = W[k*128 + n*16 + lm];
            float hi = W[(k+1)*128 + n*16 + lm];
            out[p] = (u32)f2bf(lo) | ((u32)f2bf(hi) << 16);
        }
        *(uint4*)&wtf[u*4] = make_uint4(out[0], out[1], out[2], out[3]);
    }
}

// ---- prep 2: per (b,br): y_trans (in-block) -> WeffT fragments + Cs ----
__global__ __launch_bounds__(256) void prep_weff(
    const float* __restrict__ y,    const float* __restrict__ wty,
    const float* __restrict__ bty,  const float* __restrict__ aty,
    const float* __restrict__ uid,  const float* __restrict__ ose, const float* __restrict__ zipc,
    const float* __restrict__ lw1,  const float* __restrict__ lb1,
    const float* __restrict__ nw1,  const float* __restrict__ nb1,
    u32* __restrict__ weff, float* __restrict__ cs)
{
    __shared__ float yl[64];
    __shared__ float sq[128];
    __shared__ float yv[128];
    __shared__ float cpart[240];

    const int tid = threadIdx.x;
    const int b   = blockIdx.x;
    const int br  = blockIdx.y;
    const float* w1 = br ? nw1 : lw1;
    const float* b1 = br ? nb1 : lb1;

    // --- y_trans for this b ---
    if (tid < 64) yl[tid] = y[b*64 + tid];
    __syncthreads();
    float v = 0.f;
    if (tid < 128) {
        float acc = bty[tid];
        for (int k = 0; k < 64; ++k) acc = fmaf(yl[k], wty[k*128 + tid], acc);
        float a = aty[0];
        v = (acc >= 0.f) ? acc : a * acc;
        sq[tid] = v * v;
    }
    __syncthreads();
    for (int s = 64; s >= 1; s >>= 1) { if (tid < s) sq[tid] += sq[tid+s]; __syncthreads(); }
    if (tid < 128) yv[tid] = v * (1.f / fmaxf(sqrtf(sq[0]), 1e-12f));
    __syncthreads();

    // --- WeffT fragments: unit = fragrow*64+lane, fragrow = h*6+nj*2+ks ---
    for (int u = tid; u < 768; u += 256) {
        int lane = u & 63, fr = u >> 6;
        int h = fr / 6, t = fr % 6, nj = t >> 1, ks = t & 1;
        int q = lane >> 4, lm = lane & 15, j = nj*16 + lm;
        u32 out[4];
        #pragma unroll
        for (int p = 0; p < 4; ++p) {
            u32 w = 0;
            #pragma unroll
            for (int e = 0; e < 2; ++e) {
                int k = ks*32 + q*8 + p*2 + e;
                float val = 0.f;
                if (j < 40)
                    val = w1[k*40 + j] + w1[(128+k)*40 + j] + yv[h*64 + k] * w1[(64+k)*40 + j];
                w |= ((u32)f2bf(val)) << (16*e);
            }
            out[p] = w;
        }
        *(uint4*)&weff[((size_t)(br*NB + b)*12 + fr)*64*4 + lane*4] =
            make_uint4(out[0], out[1], out[2], out[3]);
    }

    // --- Cs partials: 240 threads, cj = h*40+j, slice of 120 terms ---
    if (tid < 240) {
        int cj = tid / 3, sl = tid % 3;
        int h = cj / 40, j = cj % 40;
        float acc = 0.f;
        for (int t = sl*40; t < sl*40 + 40; ++t) {
            if (t < 64) {
                acc = fmaf(yv[h*64 + t], w1[(192+t)*40 + j] - w1[(128+t)*40 + j], acc);
            } else {
                int u = t - 64;
                float sv, wv;
                if (u < 32)      { sv = uid[b*32 + u];        wv = w1[(256+u)*40 + j]; }
                else if (u < 40) { sv = ose[b*8 + (u-32)];    wv = w1[(288+(u-32))*40 + j]; }
                else             { sv = zipc[b*16 + (u-40)];  wv = w1[(296+(u-40))*40 + j]; }
                acc = fmaf(sv, wv, acc);
            }
        }
        cpart[tid] = acc;
    }
    __syncthreads();
    if (tid < 96) {
        int h = tid / 48, jj = tid % 48;
        float val = 0.f;
        if (jj < 40) {
            int cj = h*40 + jj;
            val = b1[jj] + cpart[cj*3] + cpart[cj*3+1] + cpart[cj*3+2];
        }
        cs[(size_t)(br*NB + b)*96 + tid] = val;
    }
}

// ---- main: one block per (b,br); wave w owns subtiles {w,4+w,8+w,12+w}; barrier-free loop ----
__global__ __launch_bounds__(256, 2) void main_kernel(
    const float* __restrict__ xloc, const float* __restrict__ xnon,
    const float* __restrict__ blx,  const float* __restrict__ alx,
    const float* __restrict__ bnx,  const float* __restrict__ anx,
    const float* __restrict__ la1,  const float* __restrict__ lw2, const float* __restrict__ lb2,
    const float* __restrict__ na1,  const float* __restrict__ nw2, const float* __restrict__ nb2,
    const u32* __restrict__ wtf, const u32* __restrict__ weff, const float* __restrict__ cs,
    float* __restrict__ out)
{
    __shared__ u16   tn[4*16*136];   // per-wave 16x128 bf16 tile, stride 136 (17*16B: conflict-free b128)
    __shared__ float red[512];

    const int tid  = threadIdx.x;
    const int b    = blockIdx.x;
    const int br   = blockIdx.y;
    const int w    = tid >> 6;
    const int lane = tid & 63;
    const int q    = lane >> 4;
    const int lm   = lane & 15;

    const float* xg   = br ? xnon : xloc;
    const float* bias = br ? bnx  : blx;
    const float  ax   = br ? anx[0] : alx[0];
    const float  a1v  = br ? na1[0] : la1[0];
    const float  b2v  = br ? nb2[0] : lb2[0];
    const float* w2   = br ? nw2  : lw2;

    // ---- fragment prologue (coalesced 16B loads, L2-hot) ----
    const bf8_t* wtfv  = (const bf8_t*)wtf;
    const bf8_t* weffv = (const bf8_t*)weff + (size_t)(br*NB + b)*12*64;
    bf8_t Bfrag[8][2];
    #pragma unroll
    for (int n = 0; n < 8; ++n)
        #pragma unroll
        for (int ks = 0; ks < 2; ++ks)
            Bfrag[n][ks] = wtfv[(br*16 + n*2 + ks)*64 + lane];
    bf8_t Cfrag[2][3][2];
    #pragma unroll
    for (int h = 0; h < 2; ++h)
        #pragma unroll
        for (int nj = 0; nj < 3; ++nj)
            #pragma unroll
            for (int ks = 0; ks < 2; ++ks)
                Cfrag[h][nj][ks] = weffv[(h*6 + nj*2 + ks)*64 + lane];

    float bv[8];
    #pragma unroll
    for (int n = 0; n < 8; ++n) bv[n] = bias[n*16 + lm];
    float w2v[3];
    #pragma unroll
    for (int nj = 0; nj < 3; ++nj) w2v[nj] = (nj*16 + lm < 40) ? w2[nj*16 + lm] : 0.f;
    float Cv[2][3];
    #pragma unroll
    for (int h = 0; h < 2; ++h)
        #pragma unroll
        for (int nj = 0; nj < 3; ++nj)
            Cv[h][nj] = cs[(size_t)(br*NB + b)*96 + h*48 + nj*16 + lm];

    u16* tw = &tn[w*2176];
    const f4_t zero4 = {0.f, 0.f, 0.f, 0.f};
    float outp[8];
    #pragma unroll
    for (int n = 0; n < 8; ++n) outp[n] = 0.f;

    for (int ss = 0; ss < 4; ++ss) {
        const int s0 = (ss*4 + w)*64;
        #pragma unroll
        for (int rg = 0; rg < 4; ++rg) {
            // ---- x fragments straight from global (row = s0+rg*16+lm, k = ks*32+q*8+j) ----
            const float* xr = &xg[((size_t)b*NS + s0 + rg*16 + lm)*64];
            float4 x0 = *(const float4*)(xr + q*8);
            float4 x1 = *(const float4*)(xr + q*8 + 4);
            float4 x2 = *(const float4*)(xr + 32 + q*8);
            float4 x3 = *(const float4*)(xr + 32 + q*8 + 4);
            union { u32 u[4]; bf8_t v; } A0, A1;
            A0.u[0] = pack_trunc(x0.x, x0.y); A0.u[1] = pack_trunc(x0.z, x0.w);
            A0.u[2] = pack_trunc(x1.x, x1.y); A0.u[3] = pack_trunc(x1.z, x1.w);
            A1.u[0] = pack_trunc(x2.x, x2.y); A1.u[1] = pack_trunc(x2.z, x2.w);
            A1.u[2] = pack_trunc(x3.x, x3.y); A1.u[3] = pack_trunc(x3.z, x3.w);

            // ---- Phase B: t = prelu(x @ W + bias), 16 rows ----
            f4_t accB[8];
            #pragma unroll
            for (int n = 0; n < 8; ++n) {
                f4_t acc = __builtin_amdgcn_mfma_f32_16x16x32_bf16(A0.v, Bfrag[n][0], zero4, 0, 0, 0);
                acc      = __builtin_amdgcn_mfma_f32_16x16x32_bf16(A1.v, Bfrag[n][1], acc,   0, 0, 0);
                accB[n] = acc;
            }
            float tv[8][4];
            float ssq[4] = {0.f, 0.f, 0.f, 0.f};
            #pragma unroll
            for (int n = 0; n < 8; ++n)
                #pragma unroll
                for (int r = 0; r < 4; ++r) {
                    float vv = accB[n][r] + bv[n];
                    vv = (vv >= 0.f) ? vv : ax * vv;
                    tv[n][r] = vv;
                    ssq[r] = fmaf(vv, vv, ssq[r]);
                }
            #pragma unroll
            for (int r = 0; r < 4; ++r) {
                float s = ssq[r];
                s += __shfl_xor(s, 1);
                s += __shfl_xor(s, 2);
                s += __shfl_xor(s, 4);
                s += __shfl_xor(s, 8);
                float rinv = 1.f / fmaxf(sqrtf(s), 1e-12f);
                #pragma unroll
                for (int n = 0; n < 8; ++n) tv[n][r] *= rinv;
            }
            // tn (bf16, truncate) -> wave-private LDS for C/D->A layout transform
            #pragma unroll
            for (int n = 0; n < 8; ++n)
                #pragma unroll
                for (int r = 0; r < 4; ++r)
                    tw[(q*4+r)*136 + n*16 + lm] = (u16)(__float_as_uint(tv[n][r]) >> 16);

            // ---- Phase C: h1 = prelu(tn_h @ Weff + C); p = h1 @ w2 + b2 ----
            float pv[2][4];
            #pragma unroll
            for (int h = 0; h < 2; ++h) {
                bf8_t ac0 = *(const bf8_t*)&tw[lm*136 + h*64 + q*8];
                bf8_t ac1 = *(const bf8_t*)&tw[lm*136 + h*64 + 32 + q*8];
                float pp[4] = {0.f, 0.f, 0.f, 0.f};
                #pragma unroll
                for (int nj = 0; nj < 3; ++nj) {
                    f4_t acc = __builtin_amdgcn_mfma_f32_16x16x32_bf16(ac0, Cfrag[h][nj][0], zero4, 0, 0, 0);
                    acc      = __builtin_amdgcn_mfma_f32_16x16x32_bf16(ac1, Cfrag[h][nj][1], acc,   0, 0, 0);
                    #pragma unroll
                    for (int r = 0; r < 4; ++r) {
                        float vv = acc[r] + Cv[h][nj];
                        vv = (vv >= 0.f) ? vv : a1v * vv;
                        pp[r] = fmaf(vv, w2v[nj], pp[r]);
                    }
                }
                #pragma unroll
                for (int r = 0; r < 4; ++r) {
                    float s = pp[r];
                    s += __shfl_xor(s, 1);
                    s += __shfl_xor(s, 2);
                    s += __shfl_xor(s, 4);
                    s += __shfl_xor(s, 8);
                    pv[h][r] = s + b2v;
                }
            }

            // ---- Phase D (registers): out[col] += tn[row][col] * p[head][row] ----
            #pragma unroll
            for (int n = 0; n < 8; ++n)
                #pragma unroll
                for (int r = 0; r < 4; ++r)
                    outp[n] = fmaf(tv[n][r], pv[n >> 2][r], outp[n]);
        }
    }

    // reduce quads within wave, combine waves, direct store
    #pragma unroll
    for (int n = 0; n < 8; ++n) {
        float vv = outp[n];
        vv += __shfl_xor(vv, 16);
        vv += __shfl_xor(vv, 32);
        outp[n] = vv;
    }
    if (lane < 16) {
        #pragma unroll
        for (int n = 0; n < 8; ++n) red[w*128 + n*16 + lane] = outp[n];
    }
    __syncthreads();
    if (tid < 128) {
        float s = red[tid] + red[128 + tid] + red[256 + tid] + red[384 + tid];
        out[((size_t)br*NB + b)*128 + tid] = s;
    }
}

extern "C" void kernel_launch(void* const* d_in, const int* in_sizes, int n_in,
                              void* d_out, int out_size, void* d_ws, size_t ws_size,
                              hipStream_t stream)
{
    const float* xl  = (const float*)d_in[0];
    const float* xn  = (const float*)d_in[1];
    const float* y   = (const float*)d_in[2];
    const float* uid = (const float*)d_in[3];
    const float* ose = (const float*)d_in[4];
    const float* zp  = (const float*)d_in[5];
    const float* wty = (const float*)d_in[6];
    const float* bty = (const float*)d_in[7];
    const float* aty = (const float*)d_in[8];
    const float* wlx = (const float*)d_in[9];
    const float* blx = (const float*)d_in[10];
    const float* alx = (const float*)d_in[11];
    const float* wnx = (const float*)d_in[12];
    const float* bnx = (const float*)d_in[13];
    const float* anx = (const float*)d_in[14];
    const float* lw1 = (const float*)d_in[15];
    const float* lb1 = (const float*)d_in[16];
    const float* la1 = (const float*)d_in[17];
    const float* lw2 = (const float*)d_in[18];
    const float* lb2 = (const float*)d_in[19];
    const float* nw1 = (const float*)d_in[20];
    const float* nb1 = (const float*)d_in[21];
    const float* na1 = (const float*)d_in[22];
    const float* nw2 = (const float*)d_in[23];
    const float* nb2 = (const float*)d_in[24];

    // ws layout (16B-aligned segments)
    u32*   wtf  = (u32*)d_ws;                               // 2048*16B = 32 KB
    u32*   weff = (u32*)((char*)d_ws + 32768);              // 512*12*64*16B = 6 MB
    float* cs   = (float*)((char*)d_ws + 32768 + 6291456);  // 512*96*4 = 192 KB

    prep_wtf<<<dim3(1), dim3(256), 0, stream>>>(wlx, wnx, wtf);
    prep_weff<<<dim3(NB, 2), dim3(256), 0, stream>>>(
        y, wty, bty, aty, uid, ose, zp, lw1, lb1, nw1, nb1, weff, cs);
    main_kernel<<<dim3(NB, 2), dim3(256), 0, stream>>>(
        xl, xn, blx, alx, bnx, anx,
        la1, lw2, lb2, na1, nw2, nb2,
        wtf, weff, cs, (float*)d_out);
}

// Round 7
// 246.965 us; speedup vs baseline: 1.8242x; 1.2390x over previous
//
#include <hip/hip_runtime.h>

typedef unsigned short u16;
typedef unsigned int   u32;
typedef __attribute__((ext_vector_type(8))) short bf8_t;   // 8 x bf16 (4 VGPRs)
typedef __attribute__((ext_vector_type(4))) float f4_t;    // 4 x fp32 acc

#define NB 256
#define NS 1024

__device__ __forceinline__ u16 f2bf(float f){   // RNE (used in prep only)
    u32 u = __float_as_uint(f);
    return (u16)((u + 0x7fffu + ((u >> 16) & 1u)) >> 16);
}
__device__ __forceinline__ u32 pack_trunc(float lo, float hi){  // 2 x fp32 -> packed bf16 (truncate)
    return (__float_as_uint(hi) & 0xffff0000u) | (__float_as_uint(lo) >> 16);
}

// ---- fused prep: blocks 0..511 -> per-(b,br) WeffT fragments + Cs (+y_trans);
//                  blocks 512..519 -> W (x-transform) B-fragment layout ----
__global__ __launch_bounds__(256) void prep_kernel(
    const float* __restrict__ y,    const float* __restrict__ wty,
    const float* __restrict__ bty,  const float* __restrict__ aty,
    const float* __restrict__ uid,  const float* __restrict__ ose, const float* __restrict__ zipc,
    const float* __restrict__ wlx,  const float* __restrict__ wnx,
    const float* __restrict__ lw1,  const float* __restrict__ lb1,
    const float* __restrict__ nw1,  const float* __restrict__ nb1,
    u32* __restrict__ wtf, u32* __restrict__ weff, float* __restrict__ cs)
{
    const int tid = threadIdx.x;
    const int bx  = blockIdx.x;

    if (bx >= 512) {
        // ---- wtf part: unit u = (br*16 + n*2 + ks)*64 + lane ----
        int u = (bx - 512)*256 + tid;   // 0..2047
        int lane = u & 63, fr = u >> 6;
        int br = fr >> 4, t = fr & 15, n = t >> 1, ks = t & 1;
        int q = lane >> 4, lm = lane & 15;
        const float* W = br ? wnx : wlx;
        u32 out[4];
        #pragma unroll
        for (int p = 0; p < 4; ++p) {
            int k = ks*32 + q*8 + p*2;
            float lo = W[k*128 + n*16 + lm];
            float hi = W[(k+1)*128 + n*16 + lm];
            out[p] = (u32)f2bf(lo) | ((u32)f2bf(hi) << 16);
        }
        *(uint4*)&wtf[u*4] = make_uint4(out[0], out[1], out[2], out[3]);
        return;
    }

    __shared__ float yl[64];
    __shared__ float sq[128];
    __shared__ float yv[128];
    __shared__ float cpart[240];

    const int b  = bx >> 1;
    const int br = bx & 1;
    const float* w1 = br ? nw1 : lw1;
    const float* b1 = br ? nb1 : lb1;

    // --- y_trans for this b ---
    if (tid < 64) yl[tid] = y[b*64 + tid];
    __syncthreads();
    float v = 0.f;
    if (tid < 128) {
        float acc = bty[tid];
        for (int k = 0; k < 64; ++k) acc = fmaf(yl[k], wty[k*128 + tid], acc);
        float a = aty[0];
        v = (acc >= 0.f) ? acc : a * acc;
        sq[tid] = v * v;
    }
    __syncthreads();
    for (int s = 64; s >= 1; s >>= 1) { if (tid < s) sq[tid] += sq[tid+s]; __syncthreads(); }
    if (tid < 128) yv[tid] = v * (1.f / fmaxf(sqrtf(sq[0]), 1e-12f));
    __syncthreads();

    // --- WeffT fragments: unit = fragrow*64+lane, fragrow = h*6+nj*2+ks ---
    for (int u = tid; u < 768; u += 256) {
        int lane = u & 63, fr = u >> 6;
        int h = fr / 6, t = fr % 6, nj = t >> 1, ks = t & 1;
        int q = lane >> 4, lm = lane & 15, j = nj*16 + lm;
        u32 out[4];
        #pragma unroll
        for (int p = 0; p < 4; ++p) {
            u32 w = 0;
            #pragma unroll
            for (int e = 0; e < 2; ++e) {
                int k = ks*32 + q*8 + p*2 + e;
                float val = 0.f;
                if (j < 40)
                    val = w1[k*40 + j] + w1[(128+k)*40 + j] + yv[h*64 + k] * w1[(64+k)*40 + j];
                w |= ((u32)f2bf(val)) << (16*e);
            }
            out[p] = w;
        }
        *(uint4*)&weff[((size_t)(br*NB + b)*12 + fr)*64*4 + lane*4] =
            make_uint4(out[0], out[1], out[2], out[3]);
    }

    // --- Cs partials: 240 threads, cj = h*40+j, slice of 120 terms ---
    if (tid < 240) {
        int cj = tid / 3, sl = tid % 3;
        int h = cj / 40, j = cj % 40;
        float acc = 0.f;
        for (int t = sl*40; t < sl*40 + 40; ++t) {
            if (t < 64) {
                acc = fmaf(yv[h*64 + t], w1[(192+t)*40 + j] - w1[(128+t)*40 + j], acc);
            } else {
                int u = t - 64;
                float sv, wv;
                if (u < 32)      { sv = uid[b*32 + u];        wv = w1[(256+u)*40 + j]; }
                else if (u < 40) { sv = ose[b*8 + (u-32)];    wv = w1[(288+(u-32))*40 + j]; }
                else             { sv = zipc[b*16 + (u-40)];  wv = w1[(296+(u-40))*40 + j]; }
                acc = fmaf(sv, wv, acc);
            }
        }
        cpart[tid] = acc;
    }
    __syncthreads();
    if (tid < 96) {
        int h = tid / 48, jj = tid % 48;
        float val = 0.f;
        if (jj < 40) {
            int cj = h*40 + jj;
            val = b1[jj] + cpart[cj*3] + cpart[cj*3+1] + cpart[cj*3+2];
        }
        cs[(size_t)(br*NB + b)*96 + tid] = val;
    }
}

// ---- main: one block per (b,br,zc); wave w owns subtiles; barrier-free loop; reg prefetch ----
__global__ __launch_bounds__(256, 2) void main_kernel(
    const float* __restrict__ xloc, const float* __restrict__ xnon,
    const float* __restrict__ blx,  const float* __restrict__ alx,
    const float* __restrict__ bnx,  const float* __restrict__ anx,
    const float* __restrict__ la1,  const float* __restrict__ lw2, const float* __restrict__ lb2,
    const float* __restrict__ na1,  const float* __restrict__ nw2, const float* __restrict__ nb2,
    const u32* __restrict__ wtf, const u32* __restrict__ weff, const float* __restrict__ cs,
    float* __restrict__ out)
{
    __shared__ u16   tn[4*16*136];   // per-wave 16x128 bf16 tile, stride 136
    __shared__ float red[512];

    const int tid  = threadIdx.x;
    const int b    = blockIdx.x;
    const int br   = blockIdx.y;
    const int zc   = blockIdx.z;    // seq half
    const int w    = tid >> 6;
    const int lane = tid & 63;
    const int q    = lane >> 4;
    const int lm   = lane & 15;

    const float* xg   = br ? xnon : xloc;
    const float* bias = br ? bnx  : blx;
    const float  ax   = br ? anx[0] : alx[0];
    const float  a1v  = br ? na1[0] : la1[0];
    const float  b2v  = br ? nb2[0] : lb2[0];
    const float* w2   = br ? nw2  : lw2;

    // ---- fragment prologue (coalesced 16B loads, L2-hot) ----
    const bf8_t* wtfv  = (const bf8_t*)wtf;
    const bf8_t* weffv = (const bf8_t*)weff + (size_t)(br*NB + b)*12*64;
    bf8_t Bfrag[8][2];
    #pragma unroll
    for (int n = 0; n < 8; ++n)
        #pragma unroll
        for (int ks = 0; ks < 2; ++ks)
            Bfrag[n][ks] = wtfv[(br*16 + n*2 + ks)*64 + lane];
    bf8_t Cfrag[2][3][2];
    #pragma unroll
    for (int h = 0; h < 2; ++h)
        #pragma unroll
        for (int nj = 0; nj < 3; ++nj)
            #pragma unroll
            for (int ks = 0; ks < 2; ++ks)
                Cfrag[h][nj][ks] = weffv[(h*6 + nj*2 + ks)*64 + lane];

    float bv[8];
    #pragma unroll
    for (int n = 0; n < 8; ++n) bv[n] = bias[n*16 + lm];
    float w2v[3];
    #pragma unroll
    for (int nj = 0; nj < 3; ++nj) w2v[nj] = (nj*16 + lm < 40) ? w2[nj*16 + lm] : 0.f;
    float Cv[2][3];
    #pragma unroll
    for (int h = 0; h < 2; ++h)
        #pragma unroll
        for (int nj = 0; nj < 3; ++nj)
            Cv[h][nj] = cs[(size_t)(br*NB + b)*96 + h*48 + nj*16 + lm];

    u16* tw = &tn[w*2176];
    const f4_t zero4 = {0.f, 0.f, 0.f, 0.f};
    float outp[8];
    #pragma unroll
    for (int n = 0; n < 8; ++n) outp[n] = 0.f;

    const float* xb = &xg[(size_t)b*NS*64];
    // it = ss*4+rg; wave w row base: (zc*8 + ss*4 + w)*64 + rg*16 + lm
    #define ROWPTR(it) (xb + (size_t)((zc*8 + ((it)>>2)*4 + w)*64 + ((it)&3)*16 + lm)*64)

    float4 p0, p1, p2, p3;
    {
        const float* xr = ROWPTR(0);
        p0 = *(const float4*)(xr + q*8);
        p1 = *(const float4*)(xr + q*8 + 4);
        p2 = *(const float4*)(xr + 32 + q*8);
        p3 = *(const float4*)(xr + 32 + q*8 + 4);
    }

    #pragma unroll
    for (int it = 0; it < 8; ++it) {
        float4 c0 = p0, c1 = p1, c2 = p2, c3 = p3;
        if (it < 7) {
            const float* xr = ROWPTR(it + 1);
            p0 = *(const float4*)(xr + q*8);
            p1 = *(const float4*)(xr + q*8 + 4);
            p2 = *(const float4*)(xr + 32 + q*8);
            p3 = *(const float4*)(xr + 32 + q*8 + 4);
        }
        union { u32 u[4]; bf8_t v; } A0, A1;
        A0.u[0] = pack_trunc(c0.x, c0.y); A0.u[1] = pack_trunc(c0.z, c0.w);
        A0.u[2] = pack_trunc(c1.x, c1.y); A0.u[3] = pack_trunc(c1.z, c1.w);
        A1.u[0] = pack_trunc(c2.x, c2.y); A1.u[1] = pack_trunc(c2.z, c2.w);
        A1.u[2] = pack_trunc(c3.x, c3.y); A1.u[3] = pack_trunc(c3.z, c3.w);

        // ---- Phase B: t = prelu(x @ W + bias), 16 rows ----
        float tv[8][4];
        float ssq[4] = {0.f, 0.f, 0.f, 0.f};
        #pragma unroll
        for (int n = 0; n < 8; ++n) {
            f4_t acc = __builtin_amdgcn_mfma_f32_16x16x32_bf16(A0.v, Bfrag[n][0], zero4, 0, 0, 0);
            acc      = __builtin_amdgcn_mfma_f32_16x16x32_bf16(A1.v, Bfrag[n][1], acc,   0, 0, 0);
            #pragma unroll
            for (int r = 0; r < 4; ++r) {
                float vv = acc[r] + bv[n];
                vv = (vv >= 0.f) ? vv : ax * vv;
                tv[n][r] = vv;
                ssq[r] = fmaf(vv, vv, ssq[r]);
            }
        }
        #pragma unroll
        for (int r = 0; r < 4; ++r) {
            float s = ssq[r];
            s += __shfl_xor(s, 1);
            s += __shfl_xor(s, 2);
            s += __shfl_xor(s, 4);
            s += __shfl_xor(s, 8);
            float rinv = 1.f / fmaxf(sqrtf(s), 1e-12f);
            #pragma unroll
            for (int n = 0; n < 8; ++n) tv[n][r] *= rinv;
        }
        // tn (bf16, truncate) -> wave-private LDS for C/D->A layout transform
        #pragma unroll
        for (int n = 0; n < 8; ++n)
            #pragma unroll
            for (int r = 0; r < 4; ++r)
                tw[(q*4+r)*136 + n*16 + lm] = (u16)(__float_as_uint(tv[n][r]) >> 16);

        // ---- Phase C: h1 = prelu(tn_h @ Weff + C); p = h1 @ w2 + b2 ----
        float pv[2][4];
        #pragma unroll
        for (int h = 0; h < 2; ++h) {
            bf8_t ac0 = *(const bf8_t*)&tw[lm*136 + h*64 + q*8];
            bf8_t ac1 = *(const bf8_t*)&tw[lm*136 + h*64 + 32 + q*8];
            float pp[4] = {0.f, 0.f, 0.f, 0.f};
            #pragma unroll
            for (int nj = 0; nj < 3; ++nj) {
                f4_t acc = __builtin_amdgcn_mfma_f32_16x16x32_bf16(ac0, Cfrag[h][nj][0], zero4, 0, 0, 0);
                acc      = __builtin_amdgcn_mfma_f32_16x16x32_bf16(ac1, Cfrag[h][nj][1], acc,   0, 0, 0);
                #pragma unroll
                for (int r = 0; r < 4; ++r) {
                    float vv = acc[r] + Cv[h][nj];
                    vv = (vv >= 0.f) ? vv : a1v * vv;
                    pp[r] = fmaf(vv, w2v[nj], pp[r]);
                }
            }
            #pragma unroll
            for (int r = 0; r < 4; ++r) {
                float s = pp[r];
                s += __shfl_xor(s, 1);
                s += __shfl_xor(s, 2);
                s += __shfl_xor(s, 4);
                s += __shfl_xor(s, 8);
                pv[h][r] = s + b2v;
            }
        }

        // ---- Phase D (registers): out[col] += tn[row][col] * p[head][row] ----
        #pragma unroll
        for (int n = 0; n < 8; ++n)
            #pragma unroll
            for (int r = 0; r < 4; ++r)
                outp[n] = fmaf(tv[n][r], pv[n >> 2][r], outp[n]);
    }
    #undef ROWPTR

    // reduce quads within wave, combine waves, atomic add (seq halves)
    #pragma unroll
    for (int n = 0; n < 8; ++n) {
        float vv = outp[n];
        vv += __shfl_xor(vv, 16);
        vv += __shfl_xor(vv, 32);
        outp[n] = vv;
    }
    if (lane < 16) {
        #pragma unroll
        for (int n = 0; n < 8; ++n) red[w*128 + n*16 + lane] = outp[n];
    }
    __syncthreads();
    if (tid < 128) {
        float s = red[tid] + red[128 + tid] + red[256 + tid] + red[384 + tid];
        atomicAdd(&out[((size_t)br*NB + b)*128 + tid], s);
    }
}

extern "C" void kernel_launch(void* const* d_in, const int* in_sizes, int n_in,
                              void* d_out, int out_size, void* d_ws, size_t ws_size,
                              hipStream_t stream)
{
    const float* xl  = (const float*)d_in[0];
    const float* xn  = (const float*)d_in[1];
    const float* y   = (const float*)d_in[2];
    const float* uid = (const float*)d_in[3];
    const float* ose = (const float*)d_in[4];
    const float* zp  = (const float*)d_in[5];
    const float* wty = (const float*)d_in[6];
    const float* bty = (const float*)d_in[7];
    const float* aty = (const float*)d_in[8];
    const float* wlx = (const float*)d_in[9];
    const float* blx = (const float*)d_in[10];
    const float* alx = (const float*)d_in[11];
    const float* wnx = (const float*)d_in[12];
    const float* bnx = (const float*)d_in[13];
    const float* anx = (const float*)d_in[14];
    const float* lw1 = (const float*)d_in[15];
    const float* lb1 = (const float*)d_in[16];
    const float* la1 = (const float*)d_in[17];
    const float* lw2 = (const float*)d_in[18];
    const float* lb2 = (const float*)d_in[19];
    const float* nw1 = (const float*)d_in[20];
    const float* nb1 = (const float*)d_in[21];
    const float* na1 = (const float*)d_in[22];
    const float* nw2 = (const float*)d_in[23];
    const float* nb2 = (const float*)d_in[24];

    // ws layout (16B-aligned segments)
    u32*   wtf  = (u32*)d_ws;                               // 2048*16B = 32 KB
    u32*   weff = (u32*)((char*)d_ws + 32768);              // 512*12*64*16B = 6 MB
    float* cs   = (float*)((char*)d_ws + 32768 + 6291456);  // 512*96*4 = 192 KB

    hipMemsetAsync(d_out, 0, (size_t)out_size * sizeof(float), stream);
    prep_kernel<<<dim3(520), dim3(256), 0, stream>>>(
        y, wty, bty, aty, uid, ose, zp, wlx, wnx, lw1, lb1, nw1, nb1, wtf, weff, cs);
    main_kernel<<<dim3(NB, 2, 2), dim3(256), 0, stream>>>(
        xl, xn, blx, alx, bnx, anx,
        la1, lw2, lb2, na1, nw2, nb2,
        wtf, weff, cs, (float*)d_out);
}